// Round 3
// baseline (202.379 us; speedup 1.0000x reference)
//
#include <hip/hip_runtime.h>
#include <math.h>

#ifndef M_PI
#define M_PI 3.14159265358979323846
#endif

// JPEG base quantization tables (values are exact integers)
static __device__ const double LUM_BASE[64] = {
 16,11,10,16,24,40,51,61,
 12,12,14,19,26,58,60,55,
 14,13,16,24,40,57,69,56,
 14,17,22,29,51,87,80,62,
 18,22,37,56,68,109,103,77,
 24,35,55,64,81,104,113,92,
 49,64,78,87,103,121,120,101,
 72,92,95,98,112,100,103,99};
static __device__ const double CHROM_BASE[64] = {
 17,18,24,47,99,99,99,99,
 18,21,26,66,99,99,99,99,
 24,26,56,99,99,99,99,99,
 47,66,99,99,99,99,99,99,
 99,99,99,99,99,99,99,99,
 99,99,99,99,99,99,99,99,
 99,99,99,99,99,99,99,99,
 99,99,99,99,99,99,99,99};

// One thread = one 8x8 block of one channel, held entirely in registers.
// Workgroup = 192 threads = 3 waves; wave c handles channel c of 64 blocks
// spanning one 8-row x 512-col strip. Grid = 16 images x 64 strips = 1024.
__global__ __launch_bounds__(192) void jpeg_fwd(const float* __restrict__ img,
                                                const int* __restrict__ quality,
                                                float* __restrict__ out)
{
    __shared__ float  REC[3][8][512];  // reconstructed YCbCr strip (f32, 48KB)
    __shared__ double Md[64];          // DCT matrix, f64
    __shared__ double QT[128];         // [2][8][8] scaled quant tables, f64

    const int t    = threadIdx.x;
    const int c    = t >> 6;     // channel = wave id (wave-uniform)
    const int lane = t & 63;     // spatial block within strip

    // DCT matrix in full double precision
    if (t < 64) {
        int k = t >> 3, n = t & 7;
        double norm = (k == 0) ? sqrt(1.0 / 8.0) : sqrt(2.0 / 8.0);
        Md[t] = norm * cos(M_PI / 8.0 * ((double)n + 0.5) * (double)k);
    } else {
        int qi  = t - 64;                 // 0..127
        int tbl = qi >> 6, e = qi & 63;
        int q   = quality[0];
        q = q < 1 ? 1 : (q > 100 ? 100 : q);
        double scale = (q < 50) ? (5000.0 / (double)q) : (200.0 - 2.0 * (double)q);
        double base  = tbl ? CHROM_BASE[e] : LUM_BASE[e];
        double v = (base * scale + 50.0) / 100.0;
        v = fmin(fmax(v, 1.0), 255.0);
        QT[qi] = v;
    }
    __syncthreads();

    const int b  = blockIdx.x >> 6;   // image index
    const int by = blockIdx.x & 63;   // strip (block-row) index

    const size_t plane = 512 * 512;
    const float* p0 = img + (size_t)(b * 3) * plane + (size_t)(by * 8) * 512 + lane * 8;

    // Exact f64 YCbCr weights (same expressions as the passing round-2 kernel)
    const double W00 =  0.299,   W01 =  0.587,   W02 =  0.114;
    const double W10 = -0.1687,  W11 = -0.3313,  W12 =  0.5;
    const double W20 =  0.5,     W21 = -0.4187,  W22 = -0.0813;

    double X[8][8];

    // Phase 1: load RGB rows (coalesced float4), x*255 -> my channel's YCbCr, -128
    #pragma unroll
    for (int r = 0; r < 8; ++r) {
        const float* p = p0 + r * 512;
        float4 R0 = *(const float4*)(p);
        float4 R1 = *(const float4*)(p + 4);
        float4 G0 = *(const float4*)(p + plane);
        float4 G1 = *(const float4*)(p + plane + 4);
        float4 B0 = *(const float4*)(p + 2 * plane);
        float4 B1 = *(const float4*)(p + 2 * plane + 4);
        float rf[8] = {R0.x, R0.y, R0.z, R0.w, R1.x, R1.y, R1.z, R1.w};
        float gf[8] = {G0.x, G0.y, G0.z, G0.w, G1.x, G1.y, G1.z, G1.w};
        float bf[8] = {B0.x, B0.y, B0.z, B0.w, B1.x, B1.y, B1.z, B1.w};
        #pragma unroll
        for (int k = 0; k < 8; ++k) {
            double rr = (double)rf[k] * 255.0;
            double gg = (double)gf[k] * 255.0;
            double bb = (double)bf[k] * 255.0;
            double v;
            if (c == 0)      v = W00 * rr + W01 * gg + W02 * bb;          // + b_ycc 0
            else if (c == 1) v = W10 * rr + W11 * gg + W12 * bb + 128.0;
            else             v = W20 * rr + W21 * gg + W22 * bb + 128.0;
            X[r][k] = v - 128.0;
        }
    }

    // Phase 2: row transform (X-128) @ M^T : out[r][cc] = sum_k X[r][k]*M[cc][k]
    #pragma unroll
    for (int r = 0; r < 8; ++r) {
        double tmp[8];
        #pragma unroll
        for (int cc = 0; cc < 8; ++cc) {
            double s = 0.0;
            #pragma unroll
            for (int k = 0; k < 8; ++k)
                s += X[r][k] * Md[(cc << 3) + k];
            tmp[cc] = s;
        }
        #pragma unroll
        for (int cc = 0; cc < 8; ++cc) X[r][cc] = tmp[cc];
    }

    // Phase 3: column transform M @ tmp, then quantize: tq = rint(dct/q)*q
    // Reference quirk: table selected by flattened (b*3+ch) < bs, NOT by channel
    const int sel = ((b * 3 + c) < 16) ? 0 : 1;
    #pragma unroll
    for (int j = 0; j < 8; ++j) {
        double tmp[8];
        #pragma unroll
        for (int r = 0; r < 8; ++r) {
            double s = 0.0;
            #pragma unroll
            for (int k = 0; k < 8; ++k)
                s += Md[(r << 3) + k] * X[k][j];
            double q = QT[(sel << 6) + (r << 3) + j];
            tmp[r] = rint(s / q) * q;   // round half-to-even, like jnp.round
        }
        #pragma unroll
        for (int r = 0; r < 8; ++r) X[r][j] = tmp[r];
    }

    // Phase 4: row transform tq @ M : out[r][j] = sum_k tq[r][k]*M[k][j]
    #pragma unroll
    for (int r = 0; r < 8; ++r) {
        double tmp[8];
        #pragma unroll
        for (int j = 0; j < 8; ++j) {
            double s = 0.0;
            #pragma unroll
            for (int k = 0; k < 8; ++k)
                s += X[r][k] * Md[(k << 3) + j];
            tmp[j] = s;
        }
        #pragma unroll
        for (int j = 0; j < 8; ++j) X[r][j] = tmp[j];
    }

    // Phase 5: column transform M^T @ tmp, +128
    #pragma unroll
    for (int j = 0; j < 8; ++j) {
        double tmp[8];
        #pragma unroll
        for (int i = 0; i < 8; ++i) {
            double s = 0.0;
            #pragma unroll
            for (int k = 0; k < 8; ++k)
                s += Md[(k << 3) + i] * X[k][j];
            tmp[i] = s + 128.0;
        }
        #pragma unroll
        for (int i = 0; i < 8; ++i) X[i][j] = tmp[i];
    }

    // Stage reconstructed channel to LDS (f32; post-quantization path is smooth)
    #pragma unroll
    for (int r = 0; r < 8; ++r) {
        float4 v0 = make_float4((float)X[r][0], (float)X[r][1], (float)X[r][2], (float)X[r][3]);
        float4 v1 = make_float4((float)X[r][4], (float)X[r][5], (float)X[r][6], (float)X[r][7]);
        *(float4*)&REC[c][r][lane * 8]     = v0;
        *(float4*)&REC[c][r][lane * 8 + 4] = v1;
    }
    __syncthreads();

    // Phase 6: YCbCr -> RGB (my wave writes plane c), /255, clip, coalesced store
    float* q0 = out + (size_t)(b * 3 + c) * plane + (size_t)(by * 8) * 512 + lane * 8;
    #pragma unroll
    for (int r = 0; r < 8; ++r) {
        float o[8];
        #pragma unroll
        for (int k = 0; k < 8; ++k) {
            double y  = (double)REC[0][r][lane * 8 + k];
            double cb = (double)REC[1][r][lane * 8 + k] - 128.0;
            double cr = (double)REC[2][r][lane * 8 + k] - 128.0;
            double v;
            if (c == 0)      v = y + 1.402 * cr;
            else if (c == 1) v = y - 0.34414 * cb - 0.71414 * cr;
            else             v = y + 1.772 * cb;
            o[k] = (float)fmin(fmax(v / 255.0, 0.0), 1.0);
        }
        *(float4*)(q0 + r * 512)     = make_float4(o[0], o[1], o[2], o[3]);
        *(float4*)(q0 + r * 512 + 4) = make_float4(o[4], o[5], o[6], o[7]);
    }
}

extern "C" void kernel_launch(void* const* d_in, const int* in_sizes, int n_in,
                              void* d_out, int out_size, void* d_ws, size_t ws_size,
                              hipStream_t stream) {
    const float* img     = (const float*)d_in[0];
    const int*   quality = (const int*)d_in[1];
    float*       out     = (float*)d_out;
    // 16 images x 64 row-strips = 1024 workgroups x 192 threads
    jpeg_fwd<<<1024, 192, 0, stream>>>(img, quality, out);
}